// Round 13
// baseline (31.168 us; speedup 1.0000x reference)
//
#include <hip/hip_runtime.h>

#define HOP      256
#define SAMPLES  262144
#define NBINS    513
#define NFRAMES  1024
#define FPB      16   // frames per block, one wave per frame

__device__ __forceinline__ float2 cmul(float2 a, float2 b) {
  return make_float2(a.x * b.x - a.y * b.y, a.x * b.y + a.y * b.x);
}
__device__ __forceinline__ float2 lds_ld(const float2* p, int bo) {
  return *(const float2*)((const char*)p + bo);
}
__device__ __forceinline__ void lds_st(float2* p, int bo, float2 v) {
  *(float2*)((char*)p + bo) = v;
}
// swizzle: c = (H<<6)|(M<<3)|L -> (H<<6)|((M^(H&1))<<3)|(L^M)
__device__ __forceinline__ int swz(int c) {
  int H = c >> 6, M = (c >> 3) & 7, L = c & 7;
  return (H << 6) | ((M ^ (H & 1)) << 3) | (L ^ M);
}

// 8-point DFT, natural-order in/out, W = e^{-2pi i/8}
__device__ __forceinline__ void fft8(float2 v[8]) {
  const float R = 0.70710678118654752440f;
  float2 s0 = make_float2(v[0].x + v[4].x, v[0].y + v[4].y);
  float2 d0 = make_float2(v[0].x - v[4].x, v[0].y - v[4].y);
  float2 s1 = make_float2(v[1].x + v[5].x, v[1].y + v[5].y);
  float2 d1 = make_float2(v[1].x - v[5].x, v[1].y - v[5].y);
  float2 s2 = make_float2(v[2].x + v[6].x, v[2].y + v[6].y);
  float2 d2 = make_float2(v[2].x - v[6].x, v[2].y - v[6].y);
  float2 s3 = make_float2(v[3].x + v[7].x, v[3].y + v[7].y);
  float2 d3 = make_float2(v[3].x - v[7].x, v[3].y - v[7].y);
  float2 e1 = make_float2(R * (d1.x + d1.y), R * (d1.y - d1.x));
  float2 e2 = make_float2(d2.y, -d2.x);
  float2 e3 = make_float2(R * (d3.y - d3.x), R * (-d3.x - d3.y));
  float2 p0 = make_float2(s0.x + s2.x, s0.y + s2.y);
  float2 q0 = make_float2(s0.x - s2.x, s0.y - s2.y);
  float2 p1 = make_float2(s1.x + s3.x, s1.y + s3.y);
  float2 q1 = make_float2(s1.x - s3.x, s1.y - s3.y);
  float2 q1t = make_float2(q1.y, -q1.x);
  float2 p2 = make_float2(d0.x + e2.x, d0.y + e2.y);
  float2 q2 = make_float2(d0.x - e2.x, d0.y - e2.y);
  float2 p3 = make_float2(e1.x + e3.x, e1.y + e3.y);
  float2 q3 = make_float2(e1.x - e3.x, e1.y - e3.y);
  float2 q3t = make_float2(q3.y, -q3.x);
  v[0] = make_float2(p0.x + p1.x, p0.y + p1.y);
  v[4] = make_float2(p0.x - p1.x, p0.y - p1.y);
  v[2] = make_float2(q0.x + q1t.x, q0.y + q1t.y);
  v[6] = make_float2(q0.x - q1t.x, q0.y - q1t.y);
  v[1] = make_float2(p2.x + p3.x, p2.y + p3.y);
  v[5] = make_float2(p2.x - p3.x, p2.y - p3.y);
  v[3] = make_float2(q2.x + q3t.x, q2.y + q3t.y);
  v[7] = make_float2(q2.x - q3t.x, q2.y - q3t.y);
}

// unpack one (frame, bin): ZP = frame base, KEY = frame xor-key, SK/SM slots
#define UNPK(ZP, KEY, SK, SM, TW, R1, I1, R2, I2) {                  \
    float2 Zk = lds_ld(ZP, ((SK) ^ (KEY)) << 3);                     \
    float2 Zm = lds_ld(ZP, ((SM) ^ (KEY)) << 3);                     \
    float xer  = 0.5f * (Zk.x + Zm.x);                               \
    float xei  = 0.5f * (Zk.y - Zm.y);                               \
    float xo_r = 0.5f * (Zk.y + Zm.y);                               \
    float xo_i = -0.5f * (Zk.x - Zm.x);                              \
    float ur = (TW).x * xo_r - (TW).y * xo_i;                        \
    float ui = (TW).x * xo_i + (TW).y * xo_r;                        \
    R1 = xer + ur; I1 = xei + ui; R2 = xer - ur; I2 = ui - xei; }

__global__ __launch_bounds__(1024, 8)   // VGPR<=64 -> 2 blocks/CU
void stft_kernel(const float* __restrict__ x, const float* __restrict__ win,
                 float* __restrict__ out) {
  __shared__ float2 z[FPB * 512];  // 64 KiB

  // anti-phase probe, corrected pairing: co-resident blocks on a CU are
  // {c, c+256} (round-robin dispatch), so key on bit 8. Write-merge siblings
  // (adjacent tiles, same batch) always share a key. Sleep ~5.9us = half the
  // ~12us block period.
  if ((blockIdx.x >> 8) & 1) {
    __builtin_amdgcn_s_sleep(127);
    __builtin_amdgcn_s_sleep(95);
  }

  const int t  = threadIdx.x;
  const int b  = blockIdx.x >> 6;
  const int f0 = (blockIdx.x & 63) * FPB;

  // ---------------- FFT phase: one wave per frame, all LDS intra-wave ------
  {
    const int w = t >> 6;     // wave = frame-in-tile
    const int u = t & 63;     // lane
    const int g = u >> 3, m2l = u & 7;
    float2* zf = z + (w << 9);

    // closed-form swizzled addresses (bytes), derived from swz():
    const int A0    = (g << 3) | (m2l ^ g);
    const int B1w_e = (A0 ^ w) << 3;                              // ex1 write, even k1
    const int B1w_o = B1w_e ^ 64;                                 //            odd k1
    const int C1    = (g << 6) | ((g & 1) << 3) | m2l;
    const int B1r   = (C1 ^ w) << 3;   // ex1 read / ex2 write: ^ (72*m1)
    const int D0    = (g << 6) | ((m2l ^ (g & 1)) << 3) | m2l;
    const int B2r   = (D0 ^ w) << 3;   // ex2 read: ^ (m<<3)
    const int F0    = (m2l << 3) | (g ^ m2l);
    const int B3_e  = (F0 ^ w) << 3;                              // st3 write, even j2
    const int B3_o  = B3_e ^ 64;                                  //            odd j2

    // ---- load + window (bounds check only in first/last tile) ----
    const float* xb = x + (size_t)b * SAMPLES;
    const int fr   = f0 + w;
    const int base = fr * HOP - 384;  // pad_left = 384
    float2 r[8];
    if (f0 != 0 && f0 != (NFRAMES - FPB)) {
      const float2* xc = (const float2*)(xb + base);
      const float2* wc = (const float2*)win;
#pragma unroll
      for (int n1 = 0; n1 < 8; ++n1) {
        float2 xv = xc[(n1 << 6) + u];
        float2 wv = wc[(n1 << 6) + u];
        r[n1] = make_float2(xv.x * wv.x, xv.y * wv.y);
      }
    } else {
#pragma unroll
      for (int n1 = 0; n1 < 8; ++n1) {
        int s = (n1 << 7) + 2 * u;
        int idx = base + s;
        float2 xv = make_float2(0.f, 0.f);
        if (idx >= 0 && idx < SAMPLES) xv = *(const float2*)(xb + idx);
        float2 wv = *(const float2*)(win + s);
        r[n1] = make_float2(xv.x * wv.x, xv.y * wv.y);
      }
    }

    // ---- stage 1: radix-8, twiddle W512^{u*k1} ----
    fft8(r);
    float sn, cs;
    __sincosf((float)u * (-6.28318530717958647693f / 512.f), &sn, &cs);
    {
      float2 w1 = make_float2(cs, sn);
      float2 w2 = cmul(w1, w1);
      float2 w3 = cmul(w2, w1);
      float2 w4 = cmul(w2, w2);
      r[1] = cmul(r[1], w1);
      r[2] = cmul(r[2], w2);
      r[3] = cmul(r[3], w3);
      r[4] = cmul(r[4], w4);
      r[5] = cmul(r[5], cmul(w4, w1));
      r[6] = cmul(r[6], cmul(w4, w2));
      r[7] = cmul(r[7], cmul(w4, w3));
    }
    lds_st(zf, B1w_e,        r[0]);
    lds_st(zf, B1w_o +  512, r[1]);
    lds_st(zf, B1w_e + 1024, r[2]);
    lds_st(zf, B1w_o + 1536, r[3]);
    lds_st(zf, B1w_e + 2048, r[4]);
    lds_st(zf, B1w_o + 2560, r[5]);
    lds_st(zf, B1w_e + 3072, r[6]);
    lds_st(zf, B1w_o + 3584, r[7]);

    // ex1 read: addr = B1r ^ 72*m1
    float2 y[8];
#pragma unroll
    for (int m1 = 0; m1 < 8; ++m1) y[m1] = lds_ld(zf, B1r ^ (72 * m1));

    // ---- stage 2: radix-8, twiddle W64^{m2l*j1} ----
    fft8(y);
    __sincosf((float)m2l * (-6.28318530717958647693f / 64.f), &sn, &cs);
    {
      float2 w1 = make_float2(cs, sn);
      float2 w2 = cmul(w1, w1);
      float2 w3 = cmul(w2, w1);
      float2 w4 = cmul(w2, w2);
      y[1] = cmul(y[1], w1);
      y[2] = cmul(y[2], w2);
      y[3] = cmul(y[3], w3);
      y[4] = cmul(y[4], w4);
      y[5] = cmul(y[5], cmul(w4, w1));
      y[6] = cmul(y[6], cmul(w4, w2));
      y[7] = cmul(y[7], cmul(w4, w3));
    }
    // ex2 write: same 8 addresses as ex1 read (in-place along m1/j1)
#pragma unroll
    for (int j1 = 0; j1 < 8; ++j1) lds_st(zf, B1r ^ (72 * j1), y[j1]);

    // ex2 read: addr = B2r ^ (m<<3)
    float2 h[8];
#pragma unroll
    for (int m = 0; m < 8; ++m) h[m] = lds_ld(zf, B2r ^ (m << 3));

    // ---- stage 3 + natural-order store: addr = base_even/odd + j2*512 ----
    fft8(h);
    lds_st(zf, B3_e,        h[0]);
    lds_st(zf, B3_o +  512, h[1]);
    lds_st(zf, B3_e + 1024, h[2]);
    lds_st(zf, B3_o + 1536, h[3]);
    lds_st(zf, B3_e + 2048, h[4]);
    lds_st(zf, B3_o + 2560, h[5]);
    lds_st(zf, B3_e + 3072, h[6]);
    lds_st(zf, B3_o + 3584, h[7]);
  }
  __syncthreads();

  // -------- unpack: frame-pair per thread, float2 stores, 2 bin-steps ------
  {
    const int f2i = t & 7;        // frame-pair index: 8 lanes span 16 frames
    const int q   = t >> 3;       // bin 0..127
    const int f   = f2i << 1;
    const int fr  = f0 + f;
    const float2* zp0 = z + (f << 9);
    const float2* zp1 = z + ((f + 1) << 9);

    const int sk0 = swz(q);
    const int sm0 = swz((512 - q) & 511);
    const int sk1 = sk0 + 128;                   // swz(q+128) = swz(q)+128
    const int sm1 = (q == 0) ? 384 : (sm0 - 128);// swz(384-q); q=0 -> swz(384)

    float sn, cs;
    __sincosf((float)q * (-6.28318530717958647693f / 1024.f), &sn, &cs);
    const float2 tw0 = make_float2(cs, sn);
    const float2 tw1 = cmul(tw0, make_float2(0.70710678118654752440f,
                                             -0.70710678118654752440f));
    float* out_r = out;
    float* out_i = out + (size_t)16 * NBINS * NFRAMES;
    const size_t o1 = ((size_t)b * NBINS + q) * NFRAMES + fr;
    const size_t o2 = ((size_t)b * NBINS + (512 - q)) * NFRAMES + fr;
    const size_t STP = (size_t)128 * NFRAMES;

    // ---- k = q ----
    {
      float r1a, i1a, r2a, i2a, r1b, i1b, r2b, i2b;
      UNPK(zp0, f,     sk0, sm0, tw0, r1a, i1a, r2a, i2a)
      UNPK(zp1, f + 1, sk0, sm0, tw0, r1b, i1b, r2b, i2b)
      *(float2*)(out_r + o1) = make_float2(r1a, r1b);
      *(float2*)(out_i + o1) = make_float2(i1a, i1b);
      *(float2*)(out_r + o2) = make_float2(r2a, r2b);
      *(float2*)(out_i + o2) = make_float2(i2a, i2b);
    }
    // ---- k = q + 128 ----
    {
      float r1a, i1a, r2a, i2a, r1b, i1b, r2b, i2b;
      UNPK(zp0, f,     sk1, sm1, tw1, r1a, i1a, r2a, i2a)
      UNPK(zp1, f + 1, sk1, sm1, tw1, r1b, i1b, r2b, i2b)
      *(float2*)(out_r + o1 + STP) = make_float2(r1a, r1b);
      *(float2*)(out_i + o1 + STP) = make_float2(i1a, i1b);
      *(float2*)(out_r + o2 - STP) = make_float2(r2a, r2b);
      *(float2*)(out_i + o2 - STP) = make_float2(i2a, i2b);
    }
    // ---- edge bin 256: X[256] = conj(Z[256]) ----
    if (q == 0) {
      float2 Za = lds_ld(zp0, (256 ^ f) << 3);
      float2 Zb = lds_ld(zp1, (256 ^ (f + 1)) << 3);
      const size_t o6 = ((size_t)b * NBINS + 256) * NFRAMES + fr;
      *(float2*)(out_r + o6) = make_float2(Za.x, Zb.x);
      *(float2*)(out_i + o6) = make_float2(-Za.y, -Zb.y);
    }
  }
}

extern "C" void kernel_launch(void* const* d_in, const int* in_sizes, int n_in,
                              void* d_out, int out_size, void* d_ws, size_t ws_size,
                              hipStream_t stream) {
  const float* x = (const float*)d_in[0];
  const float* w = (const float*)d_in[1];
  float* out = (float*)d_out;
  (void)in_sizes; (void)n_in; (void)out_size; (void)d_ws; (void)ws_size;
  stft_kernel<<<dim3(1024), dim3(1024), 0, stream>>>(x, w, out);
}

// Round 14
// 23.919 us; speedup vs baseline: 1.3030x; 1.3030x over previous
//
#include <hip/hip_runtime.h>

#define HOP      256
#define SAMPLES  262144
#define NBINS    513
#define NFRAMES  1024
#define FPB      16   // frames per block, one wave per frame

__device__ __forceinline__ float2 cmul(float2 a, float2 b) {
  return make_float2(a.x * b.x - a.y * b.y, a.x * b.y + a.y * b.x);
}
__device__ __forceinline__ float2 lds_ld(const float2* p, int bo) {
  return *(const float2*)((const char*)p + bo);
}
__device__ __forceinline__ void lds_st(float2* p, int bo, float2 v) {
  *(float2*)((char*)p + bo) = v;
}
// swizzle: c = (H<<6)|(M<<3)|L -> (H<<6)|((M^(H&1))<<3)|(L^M)
__device__ __forceinline__ int swz(int c) {
  int H = c >> 6, M = (c >> 3) & 7, L = c & 7;
  return (H << 6) | ((M ^ (H & 1)) << 3) | (L ^ M);
}

// 8-point DFT, natural-order in/out, W = e^{-2pi i/8}
__device__ __forceinline__ void fft8(float2 v[8]) {
  const float R = 0.70710678118654752440f;
  float2 s0 = make_float2(v[0].x + v[4].x, v[0].y + v[4].y);
  float2 d0 = make_float2(v[0].x - v[4].x, v[0].y - v[4].y);
  float2 s1 = make_float2(v[1].x + v[5].x, v[1].y + v[5].y);
  float2 d1 = make_float2(v[1].x - v[5].x, v[1].y - v[5].y);
  float2 s2 = make_float2(v[2].x + v[6].x, v[2].y + v[6].y);
  float2 d2 = make_float2(v[2].x - v[6].x, v[2].y - v[6].y);
  float2 s3 = make_float2(v[3].x + v[7].x, v[3].y + v[7].y);
  float2 d3 = make_float2(v[3].x - v[7].x, v[3].y - v[7].y);
  float2 e1 = make_float2(R * (d1.x + d1.y), R * (d1.y - d1.x));
  float2 e2 = make_float2(d2.y, -d2.x);
  float2 e3 = make_float2(R * (d3.y - d3.x), R * (-d3.x - d3.y));
  float2 p0 = make_float2(s0.x + s2.x, s0.y + s2.y);
  float2 q0 = make_float2(s0.x - s2.x, s0.y - s2.y);
  float2 p1 = make_float2(s1.x + s3.x, s1.y + s3.y);
  float2 q1 = make_float2(s1.x - s3.x, s1.y - s3.y);
  float2 q1t = make_float2(q1.y, -q1.x);
  float2 p2 = make_float2(d0.x + e2.x, d0.y + e2.y);
  float2 q2 = make_float2(d0.x - e2.x, d0.y - e2.y);
  float2 p3 = make_float2(e1.x + e3.x, e1.y + e3.y);
  float2 q3 = make_float2(e1.x - e3.x, e1.y - e3.y);
  float2 q3t = make_float2(q3.y, -q3.x);
  v[0] = make_float2(p0.x + p1.x, p0.y + p1.y);
  v[4] = make_float2(p0.x - p1.x, p0.y - p1.y);
  v[2] = make_float2(q0.x + q1t.x, q0.y + q1t.y);
  v[6] = make_float2(q0.x - q1t.x, q0.y - q1t.y);
  v[1] = make_float2(p2.x + p3.x, p2.y + p3.y);
  v[5] = make_float2(p2.x - p3.x, p2.y - p3.y);
  v[3] = make_float2(q2.x + q3t.x, q2.y + q3t.y);
  v[7] = make_float2(q2.x - q3t.x, q2.y - q3t.y);
}

// unpack one (frame, bin); Z values are pre-halved (window folded with 0.5)
#define UNPK(ZP, KEY, SK, SM, TW, R1, I1, R2, I2) {                  \
    float2 Zk = lds_ld(ZP, ((SK) ^ (KEY)) << 3);                     \
    float2 Zm = lds_ld(ZP, ((SM) ^ (KEY)) << 3);                     \
    float xer  = Zk.x + Zm.x;                                        \
    float xei  = Zk.y - Zm.y;                                        \
    float xo_r = Zk.y + Zm.y;                                        \
    float xo_i = Zm.x - Zk.x;                                        \
    float ur = (TW).x * xo_r - (TW).y * xo_i;                        \
    float ui = (TW).x * xo_i + (TW).y * xo_r;                        \
    R1 = xer + ur; I1 = xei + ui; R2 = xer - ur; I2 = ui - xei; }

__global__ __launch_bounds__(1024, 8)   // VGPR<=64 -> 2 blocks/CU
void stft_kernel(const float* __restrict__ x, const float* __restrict__ win,
                 float* __restrict__ out) {
  __shared__ float2 z[FPB * 512];   // 64 KiB
  __shared__ float2 T1[7][64];      // stage-1 twiddles W512^{u*k}
  __shared__ float2 T2[7][8];       // stage-2 twiddles W64^{m*j}
  __shared__ float2 TU[256];        // unpack twiddles W1024^k, k<256
  __shared__ float  WH[1024];       // 0.5 * window

  const int t  = threadIdx.x;
  const int b  = blockIdx.x >> 6;
  const int f0 = (blockIdx.x & 63) * FPB;
  const int w  = t >> 6;    // wave = frame-in-tile
  const int u  = t & 63;    // lane
  const int g  = u >> 3, m2l = u & 7;

  // ---- issue raw x loads first (HBM latency hides under table fill) ----
  const float* xb = x + (size_t)b * SAMPLES;
  const int base = (f0 + w) * HOP - 384;   // pad_left = 384
  float2 r[8];
  if (f0 != 0 && f0 != (NFRAMES - FPB)) {
    const float2* xc = (const float2*)(xb + base);
#pragma unroll
    for (int n1 = 0; n1 < 8; ++n1) r[n1] = xc[(n1 << 6) + u];
  } else {
#pragma unroll
    for (int n1 = 0; n1 < 8; ++n1) {
      int idx = base + (n1 << 7) + 2 * u;
      r[n1] = make_float2(0.f, 0.f);
      if (idx >= 0 && idx < SAMPLES) r[n1] = *(const float2*)(xb + idx);
    }
  }

  // ---- cooperative table fill (waves 0-6: T1, wave 7: T2, waves 8-11: TU) --
  {
    WH[t] = 0.5f * win[t];
    float sn, cs;
    if (t < 448) {
      int k = t >> 6, uu = t & 63;
      __sincosf((float)(uu * (k + 1)) * (-6.28318530717958647693f / 512.f),
                &sn, &cs);
      T1[k][uu] = make_float2(cs, sn);
    } else if (t < 504) {
      int i = t - 448, k = i >> 3, m = i & 7;
      __sincosf((float)(m * (k + 1)) * (-6.28318530717958647693f / 64.f),
                &sn, &cs);
      T2[k][m] = make_float2(cs, sn);
    } else if (t >= 512 && t < 768) {
      int kk = t - 512;
      __sincosf((float)kk * (-6.28318530717958647693f / 1024.f), &sn, &cs);
      TU[kk] = make_float2(cs, sn);
    }
  }
  __syncthreads();

  // ---------------- FFT phase: one wave per frame, all LDS intra-wave ------
  {
    float2* zf = z + (w << 9);
    // closed-form swizzled addresses (bytes), derived from swz():
    const int A0    = (g << 3) | (m2l ^ g);
    const int B1w_e = (A0 ^ w) << 3;
    const int B1w_o = B1w_e ^ 64;
    const int C1    = (g << 6) | ((g & 1) << 3) | m2l;
    const int B1r   = (C1 ^ w) << 3;   // ex1 read / ex2 write: ^ (72*m1)
    const int D0    = (g << 6) | ((m2l ^ (g & 1)) << 3) | m2l;
    const int B2r   = (D0 ^ w) << 3;   // ex2 read: ^ (m<<3)
    const int F0    = (m2l << 3) | (g ^ m2l);
    const int B3_e  = (F0 ^ w) << 3;
    const int B3_o  = B3_e ^ 64;

    // window (pre-halved) from LDS
    const float2* wh2 = (const float2*)WH;
#pragma unroll
    for (int n1 = 0; n1 < 8; ++n1) {
      float2 wv = wh2[(n1 << 6) + u];
      r[n1] = make_float2(r[n1].x * wv.x, r[n1].y * wv.y);
    }

    // ---- stage 1: radix-8, twiddles from T1 ----
    fft8(r);
#pragma unroll
    for (int k = 1; k < 8; ++k) r[k] = cmul(r[k], T1[k - 1][u]);
    lds_st(zf, B1w_e,        r[0]);
    lds_st(zf, B1w_o +  512, r[1]);
    lds_st(zf, B1w_e + 1024, r[2]);
    lds_st(zf, B1w_o + 1536, r[3]);
    lds_st(zf, B1w_e + 2048, r[4]);
    lds_st(zf, B1w_o + 2560, r[5]);
    lds_st(zf, B1w_e + 3072, r[6]);
    lds_st(zf, B1w_o + 3584, r[7]);

    // ex1 read: addr = B1r ^ 72*m1
    float2 y[8];
#pragma unroll
    for (int m1 = 0; m1 < 8; ++m1) y[m1] = lds_ld(zf, B1r ^ (72 * m1));

    // ---- stage 2: radix-8, twiddles from T2 ----
    fft8(y);
#pragma unroll
    for (int k = 1; k < 8; ++k) y[k] = cmul(y[k], T2[k - 1][m2l]);
#pragma unroll
    for (int j1 = 0; j1 < 8; ++j1) lds_st(zf, B1r ^ (72 * j1), y[j1]);

    // ex2 read: addr = B2r ^ (m<<3)
    float2 h[8];
#pragma unroll
    for (int m = 0; m < 8; ++m) h[m] = lds_ld(zf, B2r ^ (m << 3));

    // ---- stage 3 + natural-order store ----
    fft8(h);
    lds_st(zf, B3_e,        h[0]);
    lds_st(zf, B3_o +  512, h[1]);
    lds_st(zf, B3_e + 1024, h[2]);
    lds_st(zf, B3_o + 1536, h[3]);
    lds_st(zf, B3_e + 2048, h[4]);
    lds_st(zf, B3_o + 2560, h[5]);
    lds_st(zf, B3_e + 3072, h[6]);
    lds_st(zf, B3_o + 3584, h[7]);
  }
  __syncthreads();

  // -------- unpack: frame-pair per thread, float2 stores, 2 bin-steps ------
  {
    const int f2i = t & 7;        // frame-pair index: 8 lanes span 16 frames
    const int q   = t >> 3;       // bin 0..127
    const int f   = f2i << 1;
    const int fr  = f0 + f;
    const float2* zp0 = z + (f << 9);
    const float2* zp1 = z + ((f + 1) << 9);

    const int sk0 = swz(q);
    const int sm0 = swz((512 - q) & 511);
    const int sk1 = sk0 + 128;                   // swz(q+128) = swz(q)+128
    const int sm1 = (q == 0) ? 384 : (sm0 - 128);// swz(384-q); q=0 -> swz(384)

    const float2 tw0 = TU[q];
    const float2 tw1 = TU[q + 128];
    float* out_r = out;
    float* out_i = out + (size_t)16 * NBINS * NFRAMES;
    const size_t o1 = ((size_t)b * NBINS + q) * NFRAMES + fr;
    const size_t o2 = ((size_t)b * NBINS + (512 - q)) * NFRAMES + fr;
    const size_t STP = (size_t)128 * NFRAMES;

    // ---- k = q ----
    {
      float r1a, i1a, r2a, i2a, r1b, i1b, r2b, i2b;
      UNPK(zp0, f,     sk0, sm0, tw0, r1a, i1a, r2a, i2a)
      UNPK(zp1, f + 1, sk0, sm0, tw0, r1b, i1b, r2b, i2b)
      *(float2*)(out_r + o1) = make_float2(r1a, r1b);
      *(float2*)(out_i + o1) = make_float2(i1a, i1b);
      *(float2*)(out_r + o2) = make_float2(r2a, r2b);
      *(float2*)(out_i + o2) = make_float2(i2a, i2b);
    }
    // ---- k = q + 128 ----
    {
      float r1a, i1a, r2a, i2a, r1b, i1b, r2b, i2b;
      UNPK(zp0, f,     sk1, sm1, tw1, r1a, i1a, r2a, i2a)
      UNPK(zp1, f + 1, sk1, sm1, tw1, r1b, i1b, r2b, i2b)
      *(float2*)(out_r + o1 + STP) = make_float2(r1a, r1b);
      *(float2*)(out_i + o1 + STP) = make_float2(i1a, i1b);
      *(float2*)(out_r + o2 - STP) = make_float2(r2a, r2b);
      *(float2*)(out_i + o2 - STP) = make_float2(i2a, i2b);
    }
    // ---- edge bin 256: X[256] = conj(Z[256]) = conj(2*Z') ----
    if (q == 0) {
      float2 Za = lds_ld(zp0, (256 ^ f) << 3);
      float2 Zb = lds_ld(zp1, (256 ^ (f + 1)) << 3);
      const size_t o6 = ((size_t)b * NBINS + 256) * NFRAMES + fr;
      *(float2*)(out_r + o6) = make_float2(Za.x + Za.x, Zb.x + Zb.x);
      *(float2*)(out_i + o6) = make_float2(-(Za.y + Za.y), -(Zb.y + Zb.y));
    }
  }
}

extern "C" void kernel_launch(void* const* d_in, const int* in_sizes, int n_in,
                              void* d_out, int out_size, void* d_ws, size_t ws_size,
                              hipStream_t stream) {
  const float* x = (const float*)d_in[0];
  const float* w = (const float*)d_in[1];
  float* out = (float*)d_out;
  (void)in_sizes; (void)n_in; (void)out_size; (void)d_ws; (void)ws_size;
  stft_kernel<<<dim3(1024), dim3(1024), 0, stream>>>(x, w, out);
}